// Round 6
// baseline (72.469 us; speedup 1.0000x reference)
//
#include <hip/hip_runtime.h>

// ContrastiveLoss on MI355X.
// Pipeline:
//   k1 normalize: feats fp32 [8192][128] -> nf bf16 (ws)
//   k2 fused, BARRIER-FREE: no LDS, no __syncthreads. Both MFMA operands of
//      S=nf@nf^T are contiguous 16B row-reads of nf (B-fragment lane ll holds
//      nf row 'col', k contiguous) and nf (2MB) is L2-resident, so fragments
//      load directly from global. Each of 2048 waves independently:
//        - holds its 64-row A-frags in regs (r0 from block, all 4 ms subtiles)
//        - loops 16 half-tiles (32 cols) over its private 512-col quarter:
//          issue 8 B-frag L2 loads FIRST (oldest in vmcnt FIFO), then 8
//          nontemporal HBM label loads, then 32 MFMA (vmcnt waits only reach
//          the older B batch), 32 exp2 into fixed-max sum-of-exp lacc, then
//          the label test (vmcnt 0 - latency mostly covered by compute).
//      Rationale: rounds 3-5 all plateaued ~72us because the label-scan VMEM
//      queue was drained by a test+__syncthreads every K-tile (sawtooth
//      queue, lockstep waves). Barrier-free waves keep ~47KB/CU scan bytes
//      in flight continuously -> HBM-bound at the m13 per-CU rate.
//   k3 finalize: per row lse = M + log(sum of 16 partials); pos = nf_i.nf_p/T
//   k4 reduce: mean -> d_out[0]
// ws usage: 2MB nf + 512KB lpart(16 slots) + 32KB pos_idx + bpart.

#define NN 8192
#define DD 128

typedef __bf16 bf16x8 __attribute__((ext_vector_type(8)));
typedef float f32x4 __attribute__((ext_vector_type(4)));
typedef unsigned int u32x4 __attribute__((ext_vector_type(4)));

constexpr float kM     = 1.0f / 0.07f;                    // fixed max bound (cos<=1)
constexpr float kScale = 1.4426950408889634f / 0.07f;     // log2(e)/T
constexpr float kLn2   = 0.6931471805599453f;

__device__ inline unsigned short f2bf(float f) {
  unsigned int u = __float_as_uint(f);
  unsigned int r = (u + 0x7FFFu + ((u >> 16) & 1u)) >> 16;  // RNE, no NaN inputs
  return (unsigned short)r;
}

// ---------------- k1: normalize rows, store bf16 ----------------
__global__ __launch_bounds__(256) void k_normalize(const float* __restrict__ feats,
                                                   unsigned short* __restrict__ nfb) {
  int tid = threadIdx.x;
  int lane = tid & 63;
  int row = blockIdx.x * 4 + (tid >> 6);
  float2 f = *(const float2*)(feats + (size_t)row * DD + lane * 2);
  float ss = f.x * f.x + f.y * f.y;
  #pragma unroll
  for (int m = 1; m < 64; m <<= 1) ss += __shfl_xor(ss, m);
  float rn = 1.0f / fmaxf(sqrtf(ss), 1e-8f);
  unsigned int lo = f2bf(f.x * rn), hi = f2bf(f.y * rn);
  *(unsigned int*)(nfb + (size_t)row * DD + lane * 2) = lo | (hi << 16);
}

// ---------------- k2: barrier-free fused GEMM+LSE + label scan ----------------
__global__ __launch_bounds__(256, 2) void k_fused(const unsigned short* __restrict__ nfb,
                                                  const int* __restrict__ label,
                                                  float* __restrict__ lpart,
                                                  int* __restrict__ pos_idx) {
  int g = blockIdx.x;              // 0..511
  int tid = threadIdx.x;
  int w = tid >> 6;                // wave 0..3 (independent)
  int lane = tid & 63;
  int lg = lane >> 4;              // lane group 0..3 (k-offset / C-row group)
  int ll = lane & 15;              // C column within 16-tile

  int r0 = (g >> 2) * 64;                    // 64-row band
  int cq = (g & 3) * 2048 + w * 512;         // this wave's private 512-col quarter
  int wid = g * 4 + w;                       // 0..2047

  const u32x4* L = (const u32x4*)label;
  int sbase = wid * 8192 + lane;             // vec4 units; wave scans 128KB contiguous

  // A fragments for all 64 rows: afr[ms][kc], row = r0+ms*16+ll, k = kc*32+lg*8
  bf16x8 afr[4][4];
  #pragma unroll
  for (int ms = 0; ms < 4; ms++) {
    const unsigned short* arow = nfb + (size_t)(r0 + ms * 16 + ll) * DD + lg * 8;
    #pragma unroll
    for (int kc = 0; kc < 4; kc++)
      afr[ms][kc] = *(const bf16x8*)(arow + kc * 32);
  }

  float lacc[4][4];
  #pragma unroll
  for (int ms = 0; ms < 4; ms++)
    #pragma unroll
    for (int r = 0; r < 4; r++) lacc[ms][r] = 0.f;

  for (int it = 0; it < 16; ++it) {
    int hcol = cq + it * 32;   // 32-col half-tile

    // ---- B-fragment loads FIRST (L2-resident nf; oldest in vmcnt FIFO) ----
    bf16x8 bfr[2][4];
    #pragma unroll
    for (int ns = 0; ns < 2; ns++) {
      const unsigned short* brow = nfb + (size_t)(hcol + ns * 16 + ll) * DD + lg * 8;
      #pragma unroll
      for (int kc = 0; kc < 4; kc++)
        bfr[ns][kc] = *(const bf16x8*)(brow + kc * 32);
    }

    // ---- label scan loads (HBM, nontemporal, younger than B) ----
    u32x4 sv[8];
    #pragma unroll
    for (int j = 0; j < 8; j++)
      sv[j] = __builtin_nontemporal_load(&L[sbase + it * 512 + j * 64]);

    // ---- MFMA: waits only reach the (older) B batch in the vmcnt FIFO ----
    f32x4 acc[4][2];
    #pragma unroll
    for (int ms = 0; ms < 4; ms++)
      #pragma unroll
      for (int ns = 0; ns < 2; ns++) acc[ms][ns] = (f32x4){0.f, 0.f, 0.f, 0.f};
    #pragma unroll
    for (int kc = 0; kc < 4; kc++)
      #pragma unroll
      for (int ns = 0; ns < 2; ns++)
        #pragma unroll
        for (int ms = 0; ms < 4; ms++)
          acc[ms][ns] = __builtin_amdgcn_mfma_f32_16x16x32_bf16(afr[ms][kc], bfr[ns][kc], acc[ms][ns], 0, 0, 0);

    // ---- fixed-max sum of exp; C layout: col=ll, row=lg*4+r ----
    bool mayDiag = (hcol < r0 + 64) && (hcol + 32 > r0);
    if (mayDiag) {
      #pragma unroll
      for (int ms = 0; ms < 4; ms++) {
        int growb = r0 + ms * 16 + lg * 4;
        #pragma unroll
        for (int ns = 0; ns < 2; ns++) {
          int gcol = hcol + ns * 16 + ll;
          #pragma unroll
          for (int r = 0; r < 4; r++) {
            float s = (growb + r == gcol) ? -3.0e38f : acc[ms][ns][r];
            lacc[ms][r] += __builtin_amdgcn_exp2f((s - 1.0f) * kScale);
          }
        }
      }
    } else {
      #pragma unroll
      for (int ms = 0; ms < 4; ms++)
        #pragma unroll
        for (int ns = 0; ns < 2; ns++)
          #pragma unroll
          for (int r = 0; r < 4; r++)
            lacc[ms][r] += __builtin_amdgcn_exp2f((acc[ms][ns][r] - 1.0f) * kScale);
    }

    // ---- test the scan batch (vmcnt->0; latency covered by MFMA+exp) ----
    unsigned any = 0;
    #pragma unroll
    for (int j = 0; j < 8; j++) any |= sv[j][0] | sv[j][1] | sv[j][2] | sv[j][3];
    if (any) {
      #pragma unroll
      for (int j = 0; j < 8; j++) {
        if (sv[j][0] | sv[j][1] | sv[j][2] | sv[j][3]) {
          int gi = (sbase + it * 512 + j * 64) * 4;
          int row = gi >> 13, col = gi & (NN - 1);
          if (sv[j][0] == 1u) pos_idx[row] = col;
          if (sv[j][1] == 1u) pos_idx[row] = col + 1;
          if (sv[j][2] == 1u) pos_idx[row] = col + 2;
          if (sv[j][3] == 1u) pos_idx[row] = col + 3;
        }
      }
    }
  }

  // reduce partial l across the 16 lanes (cols) of each group; per-wave slot.
  #pragma unroll
  for (int ms = 0; ms < 4; ms++)
    #pragma unroll
    for (int r = 0; r < 4; r++) {
      float v = lacc[ms][r];
      v += __shfl_xor(v, 1); v += __shfl_xor(v, 2);
      v += __shfl_xor(v, 4); v += __shfl_xor(v, 8);
      lacc[ms][r] = v;
    }
  if (ll == 0) {
    int slot = (g & 3) * 4 + w;    // 16 slots: col-strip x wave-quarter
    #pragma unroll
    for (int ms = 0; ms < 4; ms++)
      #pragma unroll
      for (int r = 0; r < 4; r++) {
        int grow = r0 + ms * 16 + lg * 4 + r;
        lpart[(size_t)slot * NN + grow] = lacc[ms][r];
      }
  }
}

// ---------------- k3: per-row lse + positive, block partial sums ----------------
__global__ __launch_bounds__(256) void k_finalize(const unsigned short* __restrict__ nfb,
                                                  const float* __restrict__ lpart,
                                                  const int* __restrict__ pos_idx,
                                                  float* __restrict__ bpart) {
  int i = blockIdx.x * 256 + threadIdx.x;
  float l = 0.f;
  #pragma unroll
  for (int s = 0; s < 16; s++) l += lpart[(size_t)s * NN + i];
  float lse = kM + __builtin_amdgcn_logf(l) * kLn2;
  int p = pos_idx[i] & (NN - 1);
  const u32x4* ri = (const u32x4*)(nfb + (size_t)i * DD);
  const u32x4* rp = (const u32x4*)(nfb + (size_t)p * DD);
  float dot = 0.f;
  #pragma unroll
  for (int c = 0; c < 16; c++) {
    u32x4 a = ri[c], bb = rp[c];
    #pragma unroll
    for (int e = 0; e < 4; e++) {
      float al = __uint_as_float(a[e] << 16), ah = __uint_as_float(a[e] & 0xFFFF0000u);
      float bl = __uint_as_float(bb[e] << 16), bh = __uint_as_float(bb[e] & 0xFFFF0000u);
      dot += al * bl + ah * bh;
    }
  }
  float val = lse - dot * kM;   // pos = dot / T
  #pragma unroll
  for (int m = 1; m < 64; m <<= 1) val += __shfl_xor(val, m);
  __shared__ float wsum[4];
  if ((threadIdx.x & 63) == 0) wsum[threadIdx.x >> 6] = val;
  __syncthreads();
  if (threadIdx.x == 0) bpart[blockIdx.x] = wsum[0] + wsum[1] + wsum[2] + wsum[3];
}

// ---------------- k4: final mean ----------------
__global__ void k_reduce(const float* __restrict__ bpart, float* __restrict__ out) {
  int t = threadIdx.x;
  float v = (t < 32) ? bpart[t] : 0.f;
  #pragma unroll
  for (int m = 1; m < 64; m <<= 1) v += __shfl_xor(v, m);
  if (t == 0) out[0] = v * (1.0f / (float)NN);
}

extern "C" void kernel_launch(void* const* d_in, const int* in_sizes, int n_in,
                              void* d_out, int out_size, void* d_ws, size_t ws_size,
                              hipStream_t stream) {
  (void)in_sizes; (void)n_in; (void)out_size; (void)ws_size;
  const float* feats = (const float*)d_in[0];
  const int* label = (const int*)d_in[1];
  float* out = (float*)d_out;

  char* ws = (char*)d_ws;
  unsigned short* nfb = (unsigned short*)ws;                    // 2 MB
  float* lpart = (float*)(ws + 2 * 1024 * 1024);                // 512 KB (16 slots)
  int* pos_idx = (int*)(ws + 2 * 1024 * 1024 + 524288);         // 32 KB
  float* bpart = (float*)(ws + 2 * 1024 * 1024 + 524288 + 32768);

  k_normalize<<<NN / 4, 256, 0, stream>>>(feats, nfb);
  k_fused<<<512, 256, 0, stream>>>(nfb, label, lpart, pos_idx);
  k_finalize<<<NN / 256, 256, 0, stream>>>(nfb, lpart, pos_idx, bpart);
  k_reduce<<<1, 64, 0, stream>>>(bpart, out);
}

// Round 7
// 72.440 us; speedup vs baseline: 1.0004x; 1.0004x over previous
//
#include <hip/hip_runtime.h>

// ContrastiveLoss on MI355X.
// Pipeline:
//   k1 normalize: feats fp32 [8192][128] -> nf bf16 (ws)
//   k2 fused, barrier-free + 2-DEEP SCAN PIPELINE: waves independent (no LDS,
//      no syncthreads). Per 32-col half-tile iteration:
//        B-frag loads (L2-resident nf) -> PREFETCH scan batch it+1 ->
//        MFMA+exp (fixed-max sum-of-exp) -> TEST scan batch it (issued one
//        full iteration ago -> its vmcnt wait is already satisfied).
//      Rationale: rounds 3-6 all tested the scan batch in the issuing
//      iteration -> s_waitcnt vmcnt(0) drained the VMEM queue every iteration
//      (sawtooth in-flight, waves phase-locked) -> label stream capped ~4.3
//      TB/s regardless of macro-structure. Prefetch-ahead keeps >=1 batch
//      (8KB/wave) in flight continuously.
//   k3 finalize: per row lse = M + log(sum of 16 partials); pos = nf_i.nf_p/T
//   k4 reduce: mean -> d_out[0]
// ws usage: 2MB nf + 512KB lpart(16 slots) + 32KB pos_idx + bpart.

#define NN 8192
#define DD 128

typedef __bf16 bf16x8 __attribute__((ext_vector_type(8)));
typedef float f32x4 __attribute__((ext_vector_type(4)));
typedef unsigned int u32x4 __attribute__((ext_vector_type(4)));

constexpr float kM     = 1.0f / 0.07f;                    // fixed max bound (cos<=1)
constexpr float kScale = 1.4426950408889634f / 0.07f;     // log2(e)/T
constexpr float kLn2   = 0.6931471805599453f;

__device__ inline unsigned short f2bf(float f) {
  unsigned int u = __float_as_uint(f);
  unsigned int r = (u + 0x7FFFu + ((u >> 16) & 1u)) >> 16;  // RNE, no NaN inputs
  return (unsigned short)r;
}

// ---------------- k1: normalize rows, store bf16 ----------------
__global__ __launch_bounds__(256) void k_normalize(const float* __restrict__ feats,
                                                   unsigned short* __restrict__ nfb) {
  int tid = threadIdx.x;
  int lane = tid & 63;
  int row = blockIdx.x * 4 + (tid >> 6);
  float2 f = *(const float2*)(feats + (size_t)row * DD + lane * 2);
  float ss = f.x * f.x + f.y * f.y;
  #pragma unroll
  for (int m = 1; m < 64; m <<= 1) ss += __shfl_xor(ss, m);
  float rn = 1.0f / fmaxf(sqrtf(ss), 1e-8f);
  unsigned int lo = f2bf(f.x * rn), hi = f2bf(f.y * rn);
  *(unsigned int*)(nfb + (size_t)row * DD + lane * 2) = lo | (hi << 16);
}

// One fused step: GEMM half-tile IT + prefetch scan batch IT+1 into SVP
// + test scan batch IT from SVT (issued one iteration earlier).
#define FSTEP(IT, SVT, SVP)                                                   \
  {                                                                           \
    const int hcol = cq + (IT) * 32;                                          \
    /* B-fragment loads first (oldest in vmcnt FIFO; L2-resident nf) */       \
    bf16x8 bfr[2][4];                                                         \
    _Pragma("unroll")                                                         \
    for (int ns = 0; ns < 2; ns++) {                                          \
      const unsigned short* brow =                                            \
          nfb + (size_t)(hcol + ns * 16 + ll) * DD + lg * 8;                  \
      _Pragma("unroll")                                                       \
      for (int kc = 0; kc < 4; kc++)                                          \
        bfr[ns][kc] = *(const bf16x8*)(brow + kc * 32);                       \
    }                                                                         \
    /* prefetch NEXT scan batch (queue never empties across the body) */      \
    if ((IT) < 15) {                                                          \
      _Pragma("unroll")                                                       \
      for (int j = 0; j < 8; j++)                                             \
        SVP[j] = __builtin_nontemporal_load(                                  \
            &L[sbase + ((IT) + 1) * 512 + j * 64]);                           \
    }                                                                         \
    /* MFMA */                                                                \
    f32x4 acc[4][2];                                                          \
    _Pragma("unroll")                                                         \
    for (int ms = 0; ms < 4; ms++)                                            \
      _Pragma("unroll")                                                       \
      for (int ns = 0; ns < 2; ns++) acc[ms][ns] = (f32x4){0.f, 0.f, 0.f, 0.f};\
    _Pragma("unroll")                                                         \
    for (int kc = 0; kc < 4; kc++)                                            \
      _Pragma("unroll")                                                       \
      for (int ns = 0; ns < 2; ns++)                                          \
        _Pragma("unroll")                                                     \
        for (int ms = 0; ms < 4; ms++)                                        \
          acc[ms][ns] = __builtin_amdgcn_mfma_f32_16x16x32_bf16(              \
              afr[ms][kc], bfr[ns][kc], acc[ms][ns], 0, 0, 0);                \
    /* fixed-max sum of exp; C layout: col=ll, row=lg*4+r */                  \
    bool mayDiag = (hcol < r0 + 64) && (hcol + 32 > r0);                      \
    if (mayDiag) {                                                            \
      _Pragma("unroll")                                                       \
      for (int ms = 0; ms < 4; ms++) {                                        \
        int growb = r0 + ms * 16 + lg * 4;                                    \
        _Pragma("unroll")                                                     \
        for (int ns = 0; ns < 2; ns++) {                                      \
          int gcol = hcol + ns * 16 + ll;                                     \
          _Pragma("unroll")                                                   \
          for (int r = 0; r < 4; r++) {                                       \
            float s = (growb + r == gcol) ? -3.0e38f : acc[ms][ns][r];        \
            lacc[ms][r] += __builtin_amdgcn_exp2f((s - 1.0f) * kScale);       \
          }                                                                   \
        }                                                                     \
      }                                                                       \
    } else {                                                                  \
      _Pragma("unroll")                                                       \
      for (int ms = 0; ms < 4; ms++)                                          \
        _Pragma("unroll")                                                     \
        for (int ns = 0; ns < 2; ns++)                                        \
          _Pragma("unroll")                                                   \
          for (int r = 0; r < 4; r++)                                         \
            lacc[ms][r] +=                                                    \
                __builtin_amdgcn_exp2f((acc[ms][ns][r] - 1.0f) * kScale);     \
    }                                                                         \
    /* test scan batch IT (loaded one iteration ago; wait already met) */     \
    unsigned any = 0;                                                         \
    _Pragma("unroll")                                                         \
    for (int j = 0; j < 8; j++)                                               \
      any |= SVT[j][0] | SVT[j][1] | SVT[j][2] | SVT[j][3];                   \
    if (any) {                                                                \
      _Pragma("unroll")                                                       \
      for (int j = 0; j < 8; j++) {                                           \
        if (SVT[j][0] | SVT[j][1] | SVT[j][2] | SVT[j][3]) {                  \
          int gi = (sbase + (IT) * 512 + j * 64) * 4;                         \
          int row = gi >> 13, col = gi & (NN - 1);                            \
          if (SVT[j][0] == 1u) pos_idx[row] = col;                            \
          if (SVT[j][1] == 1u) pos_idx[row] = col + 1;                        \
          if (SVT[j][2] == 1u) pos_idx[row] = col + 2;                        \
          if (SVT[j][3] == 1u) pos_idx[row] = col + 3;                        \
        }                                                                     \
      }                                                                       \
    }                                                                         \
  }

// ---------------- k2: barrier-free fused GEMM+LSE + pipelined label scan ----
__global__ __launch_bounds__(256, 2) void k_fused(const unsigned short* __restrict__ nfb,
                                                  const int* __restrict__ label,
                                                  float* __restrict__ lpart,
                                                  int* __restrict__ pos_idx) {
  int g = blockIdx.x;              // 0..511
  int tid = threadIdx.x;
  int w = tid >> 6;                // wave 0..3 (independent)
  int lane = tid & 63;
  int lg = lane >> 4;              // lane group 0..3 (k-offset / C-row group)
  int ll = lane & 15;              // C column within 16-tile

  int r0 = (g >> 2) * 64;                    // 64-row band
  int cq = (g & 3) * 2048 + w * 512;         // this wave's private 512-col quarter
  int wid = g * 4 + w;                       // 0..2047

  const u32x4* L = (const u32x4*)label;
  int sbase = wid * 8192 + lane;             // vec4 units; wave scans 128KB contiguous

  // A fragments for all 64 rows: afr[ms][kc], row = r0+ms*16+ll, k = kc*32+lg*8
  bf16x8 afr[4][4];
  #pragma unroll
  for (int ms = 0; ms < 4; ms++) {
    const unsigned short* arow = nfb + (size_t)(r0 + ms * 16 + ll) * DD + lg * 8;
    #pragma unroll
    for (int kc = 0; kc < 4; kc++)
      afr[ms][kc] = *(const bf16x8*)(arow + kc * 32);
  }

  float lacc[4][4];
  #pragma unroll
  for (int ms = 0; ms < 4; ms++)
    #pragma unroll
    for (int r = 0; r < 4; r++) lacc[ms][r] = 0.f;

  // prologue: issue scan batch 0
  u32x4 svA[8], svB[8];
  #pragma unroll
  for (int j = 0; j < 8; j++)
    svA[j] = __builtin_nontemporal_load(&L[sbase + j * 64]);

  // 16 half-tiles, ping-pong scan batches (test lags issue by one iteration)
  for (int it2 = 0; it2 < 8; ++it2) {
    int it = it2 * 2;
    FSTEP(it,     svA, svB);   // tests batch it,   prefetches it+1 into svB
    FSTEP(it + 1, svB, svA);   // tests batch it+1, prefetches it+2 into svA
  }

  // reduce partial l across the 16 lanes (cols) of each group; per-wave slot.
  #pragma unroll
  for (int ms = 0; ms < 4; ms++)
    #pragma unroll
    for (int r = 0; r < 4; r++) {
      float v = lacc[ms][r];
      v += __shfl_xor(v, 1); v += __shfl_xor(v, 2);
      v += __shfl_xor(v, 4); v += __shfl_xor(v, 8);
      lacc[ms][r] = v;
    }
  if (ll == 0) {
    int slot = (g & 3) * 4 + w;    // 16 slots: col-strip x wave-quarter
    #pragma unroll
    for (int ms = 0; ms < 4; ms++)
      #pragma unroll
      for (int r = 0; r < 4; r++) {
        int grow = r0 + ms * 16 + lg * 4 + r;
        lpart[(size_t)slot * NN + grow] = lacc[ms][r];
      }
  }
}

// ---------------- k3: per-row lse + positive, block partial sums ----------------
__global__ __launch_bounds__(256) void k_finalize(const unsigned short* __restrict__ nfb,
                                                  const float* __restrict__ lpart,
                                                  const int* __restrict__ pos_idx,
                                                  float* __restrict__ bpart) {
  int i = blockIdx.x * 256 + threadIdx.x;
  float l = 0.f;
  #pragma unroll
  for (int s = 0; s < 16; s++) l += lpart[(size_t)s * NN + i];
  float lse = kM + __builtin_amdgcn_logf(l) * kLn2;
  int p = pos_idx[i] & (NN - 1);
  const u32x4* ri = (const u32x4*)(nfb + (size_t)i * DD);
  const u32x4* rp = (const u32x4*)(nfb + (size_t)p * DD);
  float dot = 0.f;
  #pragma unroll
  for (int c = 0; c < 16; c++) {
    u32x4 a = ri[c], bb = rp[c];
    #pragma unroll
    for (int e = 0; e < 4; e++) {
      float al = __uint_as_float(a[e] << 16), ah = __uint_as_float(a[e] & 0xFFFF0000u);
      float bl = __uint_as_float(bb[e] << 16), bh = __uint_as_float(bb[e] & 0xFFFF0000u);
      dot += al * bl + ah * bh;
    }
  }
  float val = lse - dot * kM;   // pos = dot / T
  #pragma unroll
  for (int m = 1; m < 64; m <<= 1) val += __shfl_xor(val, m);
  __shared__ float wsum[4];
  if ((threadIdx.x & 63) == 0) wsum[threadIdx.x >> 6] = val;
  __syncthreads();
  if (threadIdx.x == 0) bpart[blockIdx.x] = wsum[0] + wsum[1] + wsum[2] + wsum[3];
}

// ---------------- k4: final mean ----------------
__global__ void k_reduce(const float* __restrict__ bpart, float* __restrict__ out) {
  int t = threadIdx.x;
  float v = (t < 32) ? bpart[t] : 0.f;
  #pragma unroll
  for (int m = 1; m < 64; m <<= 1) v += __shfl_xor(v, m);
  if (t == 0) out[0] = v * (1.0f / (float)NN);
}

extern "C" void kernel_launch(void* const* d_in, const int* in_sizes, int n_in,
                              void* d_out, int out_size, void* d_ws, size_t ws_size,
                              hipStream_t stream) {
  (void)in_sizes; (void)n_in; (void)out_size; (void)ws_size;
  const float* feats = (const float*)d_in[0];
  const int* label = (const int*)d_in[1];
  float* out = (float*)d_out;

  char* ws = (char*)d_ws;
  unsigned short* nfb = (unsigned short*)ws;                    // 2 MB
  float* lpart = (float*)(ws + 2 * 1024 * 1024);                // 512 KB (16 slots)
  int* pos_idx = (int*)(ws + 2 * 1024 * 1024 + 524288);         // 32 KB
  float* bpart = (float*)(ws + 2 * 1024 * 1024 + 524288 + 32768);

  k_normalize<<<NN / 4, 256, 0, stream>>>(feats, nfb);
  k_fused<<<512, 256, 0, stream>>>(nfb, label, lpart, pos_idx);
  k_finalize<<<NN / 256, 256, 0, stream>>>(nfb, lpart, pos_idx, bpart);
  k_reduce<<<1, 64, 0, stream>>>(bpart, out);
}